// Round 1
// baseline (3164.838 us; speedup 1.0000x reference)
//
#include <hip/hip_runtime.h>
#include <math.h>

#define N_NODES 100000
#define CH 64
#define N_EDGES 1600000
#define N_PAIRS 200000

// ---------------------------------------------------------------------------
// Kernel 1: degree count.  cnt[n] = #edges with dst==n  (as float, exact)
// ---------------------------------------------------------------------------
__global__ void deg_kernel(const int* __restrict__ dst, float* __restrict__ cnt) {
    for (int e = blockIdx.x * blockDim.x + threadIdx.x; e < N_EDGES;
         e += gridDim.x * blockDim.x) {
        atomicAdd(&cnt[dst[e]], 1.0f);
    }
}

// ---------------------------------------------------------------------------
// Kernel 2: scatter-add aggregation.  agg[dst] += feat[src]  (64 ch)
// 16 lanes per edge, each lane handles 4 consecutive channels (float4 gather).
// ---------------------------------------------------------------------------
__global__ void scatter_kernel(const float* __restrict__ feat,
                               const int* __restrict__ src,
                               const int* __restrict__ dst,
                               float* __restrict__ agg) {
    int gtid = blockIdx.x * blockDim.x + threadIdx.x;
    int wave = gtid >> 6;
    int lane = gtid & 63;
    int e = wave * 4 + (lane >> 4);          // 4 edges per wave
    if (e >= N_EDGES) return;
    int s = src[e];
    int d = dst[e];
    int c4 = lane & 15;                       // float4 slot 0..15
    const float4 v = ((const float4*)(feat + (size_t)s * CH))[c4];
    float* ap = agg + (size_t)d * CH + c4 * 4;
    atomicAdd(ap + 0, v.x);
    atomicAdd(ap + 1, v.y);
    atomicAdd(ap + 2, v.z);
    atomicAdd(ap + 3, v.w);
}

// ---------------------------------------------------------------------------
// Kernel 3: node transform  out = act( (agg/cnt) @ Wl + xin @ Wr + b )
// 256 threads = 4 nodes/block, lane = output channel. Weights in LDS.
// ---------------------------------------------------------------------------
template <bool RELU>
__global__ void node_xform(const float* __restrict__ agg,
                           const float* __restrict__ cnt,
                           const float* __restrict__ xin,
                           const float* __restrict__ Wl,
                           const float* __restrict__ Wr,
                           const float* __restrict__ b,
                           float* __restrict__ out) {
    __shared__ float sWl[CH * CH];
    __shared__ float sWr[CH * CH];
    __shared__ float sB[CH];
    __shared__ float sM[4][CH];
    __shared__ float sX[4][CH];

    int tid = threadIdx.x;
    for (int i = tid; i < CH * CH; i += 256) {
        sWl[i] = Wl[i];
        sWr[i] = Wr[i];
    }
    if (tid < CH) sB[tid] = b[tid];
    __syncthreads();

    int slot = tid >> 6;
    int lane = tid & 63;

    for (int n0 = blockIdx.x * 4; n0 < N_NODES; n0 += gridDim.x * 4) {
        int n = n0 + slot;
        if (n < N_NODES) {
            float invc = 1.0f / fmaxf(cnt[n], 1.0f);
            sM[slot][lane] = agg[(size_t)n * CH + lane] * invc;
            sX[slot][lane] = xin[(size_t)n * CH + lane];
        }
        __syncthreads();
        if (n < N_NODES) {
            float acc = sB[lane];
#pragma unroll
            for (int k = 0; k < CH; k++) {
                acc += sM[slot][k] * sWl[k * CH + lane] +
                       sX[slot][k] * sWr[k * CH + lane];
            }
            if (RELU) acc = fmaxf(acc, 0.0f);
            out[(size_t)n * CH + lane] = acc;
        }
        __syncthreads();
    }
}

// ---------------------------------------------------------------------------
// Kernel 4: pair MLP.  out[p] = sigmoid( relu([h[a],h[c]] @ Wp1 + bp1) @ Wp2 + bp2 )
// 64 lanes per pair (one per hidden unit), 4 pairs per 256-thread block.
// ---------------------------------------------------------------------------
__global__ void pair_mlp(const float* __restrict__ h,
                         const int* __restrict__ p0,
                         const int* __restrict__ p1,
                         const float* __restrict__ Wp1,
                         const float* __restrict__ bp1,
                         const float* __restrict__ Wp2,
                         const float* __restrict__ bp2,
                         float* __restrict__ out) {
    __shared__ float sW1[2 * CH * CH];   // 128 x 64
    __shared__ float sB1[CH];
    __shared__ float sW2[CH];
    __shared__ float sPair[4][2 * CH];

    int tid = threadIdx.x;
    for (int i = tid; i < 2 * CH * CH; i += 256) sW1[i] = Wp1[i];
    if (tid < CH) {
        sB1[tid] = bp1[tid];
        sW2[tid] = Wp2[tid];
    }
    __syncthreads();

    int slot = tid >> 6;
    int lane = tid & 63;
    float b2v = bp2[0];

    for (int q0 = blockIdx.x * 4; q0 < N_PAIRS; q0 += gridDim.x * 4) {
        int q = q0 + slot;
        if (q < N_PAIRS) {
            int a = p0[q];
            int c = p1[q];
            sPair[slot][lane]      = h[(size_t)a * CH + lane];
            sPair[slot][CH + lane] = h[(size_t)c * CH + lane];
        }
        __syncthreads();
        if (q < N_PAIRS) {
            float z = sB1[lane];
#pragma unroll
            for (int i = 0; i < 2 * CH; i++) {
                z += sPair[slot][i] * sW1[i * CH + lane];
            }
            z = fmaxf(z, 0.0f);
            float t = z * sW2[lane];
#pragma unroll
            for (int off = 32; off; off >>= 1) t += __shfl_down(t, off);
            if (lane == 0) {
                float logit = t + b2v;
                out[q] = 1.0f / (1.0f + expf(-logit));
            }
        }
        __syncthreads();
    }
}

// ---------------------------------------------------------------------------
extern "C" void kernel_launch(void* const* d_in, const int* in_sizes, int n_in,
                              void* d_out, int out_size, void* d_ws, size_t ws_size,
                              hipStream_t stream) {
    const float* x   = (const float*)d_in[0];
    const int*   ei  = (const int*)d_in[1];   // [2, E] row-major
    const int*   ep  = (const int*)d_in[2];   // [2, P]
    const float* W1l = (const float*)d_in[3];
    const float* W1r = (const float*)d_in[4];
    const float* b1  = (const float*)d_in[5];
    const float* W2l = (const float*)d_in[6];
    const float* W2r = (const float*)d_in[7];
    const float* b2  = (const float*)d_in[8];
    const float* Wp1 = (const float*)d_in[9];
    const float* bp1 = (const float*)d_in[10];
    const float* Wp2 = (const float*)d_in[11];
    const float* bp2 = (const float*)d_in[12];
    float* out = (float*)d_out;

    const int* e_src = ei;
    const int* e_dst = ei + N_EDGES;
    const int* p_a   = ep;
    const int* p_b   = ep + N_PAIRS;

    float* agg = (float*)d_ws;                       // 6.4M floats
    float* h   = agg + (size_t)N_NODES * CH;         // 6.4M floats
    float* cnt = h + (size_t)N_NODES * CH;           // 100k floats

    // degree counts (shared by both layers)
    hipMemsetAsync(cnt, 0, N_NODES * sizeof(float), stream);
    deg_kernel<<<2048, 256, 0, stream>>>(e_dst, cnt);

    const int scatter_blocks = (N_EDGES * 16 + 255) / 256;  // 16 lanes/edge

    // ---- layer 1 ----
    hipMemsetAsync(agg, 0, (size_t)N_NODES * CH * sizeof(float), stream);
    scatter_kernel<<<scatter_blocks, 256, 0, stream>>>(x, e_src, e_dst, agg);
    node_xform<true><<<2048, 256, 0, stream>>>(agg, cnt, x, W1l, W1r, b1, h);

    // ---- layer 2 (in-place on h) ----
    hipMemsetAsync(agg, 0, (size_t)N_NODES * CH * sizeof(float), stream);
    scatter_kernel<<<scatter_blocks, 256, 0, stream>>>(h, e_src, e_dst, agg);
    node_xform<false><<<2048, 256, 0, stream>>>(agg, cnt, h, W2l, W2r, b2, h);

    // ---- link predictor ----
    pair_mlp<<<2048, 256, 0, stream>>>(h, p_a, p_b, Wp1, bp1, Wp2, bp2, out);
}

// Round 2
// 680.864 us; speedup vs baseline: 4.6483x; 4.6483x over previous
//
#include <hip/hip_runtime.h>
#include <math.h>

#define N_NODES 100000
#define CH 64
#define N_EDGES 1600000
#define N_PAIRS 200000

#define SCAN_CHUNK 512
#define SCAN_NBLK ((N_NODES + SCAN_CHUNK - 1) / SCAN_CHUNK)   // 196

// ---------------------------------------------------------------------------
// CSR build step 1: histogram of dst
// ---------------------------------------------------------------------------
__global__ void k_hist(const int* __restrict__ dst, int* __restrict__ cnt) {
    for (int e = blockIdx.x * blockDim.x + threadIdx.x; e < N_EDGES;
         e += gridDim.x * blockDim.x) {
        atomicAdd(&cnt[dst[e]], 1);
    }
}

// CSR build step 2a: per-chunk sums (one wave per 512-node chunk)
__global__ void k_chunk_sum(const int* __restrict__ cnt, int* __restrict__ partial) {
    int b = blockIdx.x;
    int lane = threadIdx.x;            // 64 threads
    int base = b * SCAN_CHUNK;
    int s = 0;
    for (int j = lane; j < SCAN_CHUNK; j += 64) {
        int idx = base + j;
        if (idx < N_NODES) s += cnt[idx];
    }
#pragma unroll
    for (int off = 32; off; off >>= 1) s += __shfl_down(s, off);
    if (lane == 0) partial[b] = s;
}

// CSR build step 2b: exclusive scan of 196 chunk sums (single thread, tiny)
__global__ void k_scan_partials(int* __restrict__ partial, int* __restrict__ row_start) {
    if (threadIdx.x == 0 && blockIdx.x == 0) {
        int run = 0;
#pragma unroll 4
        for (int i = 0; i < SCAN_NBLK; i++) {
            int t = partial[i];
            partial[i] = run;
            run += t;
        }
        row_start[N_NODES] = run;      // == N_EDGES
    }
}

// CSR build step 2c: per-chunk exclusive scan (one wave per chunk, 8 elems/lane)
__global__ void k_chunk_scan(const int* __restrict__ cnt, const int* __restrict__ partial,
                             int* __restrict__ row_start, int* __restrict__ cursor) {
    int b = blockIdx.x;
    int lane = threadIdx.x;            // 64 threads
    int base = b * SCAN_CHUNK + lane * 8;
    int v[8];
    int s = 0;
#pragma unroll
    for (int j = 0; j < 8; j++) {
        int idx = base + j;
        v[j] = (idx < N_NODES) ? cnt[idx] : 0;
        s += v[j];
    }
    int incl = s;
#pragma unroll
    for (int off = 1; off < 64; off <<= 1) {
        int t = __shfl_up(incl, off);
        if (lane >= off) incl += t;
    }
    int run = partial[b] + (incl - s); // exclusive prefix of this lane's sub-chunk
#pragma unroll
    for (int j = 0; j < 8; j++) {
        int idx = base + j;
        if (idx < N_NODES) { row_start[idx] = run; cursor[idx] = run; }
        run += v[j];
    }
}

// CSR build step 3: bucket edge sources by dst
__global__ void k_fill(const int* __restrict__ src, const int* __restrict__ dst,
                       int* __restrict__ cursor, int* __restrict__ csr) {
    for (int e = blockIdx.x * blockDim.x + threadIdx.x; e < N_EDGES;
         e += gridDim.x * blockDim.x) {
        int pos = atomicAdd(&cursor[dst[e]], 1);
        csr[pos] = src[e];
    }
}

// ---------------------------------------------------------------------------
// Fused SAGE layer: pull-gather mean + GEMV pair.  One wave per node.
//   out[n] = act( mean_{s in N(n)} feat[s] @ Wl + feat[n] @ Wr + b )
// ---------------------------------------------------------------------------
template <bool RELU>
__global__ void sage_layer(const float* __restrict__ feat,
                           const int* __restrict__ row_start,
                           const int* __restrict__ csr,
                           const float* __restrict__ Wl,
                           const float* __restrict__ Wr,
                           const float* __restrict__ b,
                           float* __restrict__ out) {
    __shared__ float sWl[CH * CH];
    __shared__ float sWr[CH * CH];
    __shared__ float sM[4][CH];
    __shared__ float sX[4][CH];

    int tid = threadIdx.x;
    for (int i = tid; i < CH * CH; i += 256) { sWl[i] = Wl[i]; sWr[i] = Wr[i]; }
    __syncthreads();

    int wslot = tid >> 6;
    int lane  = tid & 63;
    int grp   = lane >> 4;     // neighbor slot 0..3
    int c4    = lane & 15;     // float4 channel quad
    float bias = b[lane];

    for (int n0 = blockIdx.x * 4; n0 < N_NODES; n0 += gridDim.x * 4) {
        int n = n0 + wslot;
        if (n < N_NODES) {
            int beg = row_start[n];
            int end = row_start[n + 1];
            float ax = 0.f, ay = 0.f, az = 0.f, aw = 0.f;
            // 4 neighbors in flight per wave; 16 lanes x float4 = 256B row read
            for (int i = beg + grp; i < end; i += 4) {
                int s = csr[i];
                float4 v = ((const float4*)(feat + (size_t)s * CH))[c4];
                ax += v.x; ay += v.y; az += v.z; aw += v.w;
            }
            // reduce the 4 neighbor-slot partials
            ax += __shfl_xor(ax, 16); ay += __shfl_xor(ay, 16);
            az += __shfl_xor(az, 16); aw += __shfl_xor(aw, 16);
            ax += __shfl_xor(ax, 32); ay += __shfl_xor(ay, 32);
            az += __shfl_xor(az, 32); aw += __shfl_xor(aw, 32);
            float invc = 1.0f / fmaxf((float)(end - beg), 1.0f);
            if (grp == 0) {
                float4 m4 = make_float4(ax * invc, ay * invc, az * invc, aw * invc);
                ((float4*)&sM[wslot][0])[c4] = m4;
            }
            sX[wslot][lane] = feat[(size_t)n * CH + lane];
        }
        __syncthreads();
        if (n < N_NODES) {
            float acc = bias;
#pragma unroll
            for (int k = 0; k < CH; k++) {
                acc += sM[wslot][k] * sWl[k * CH + lane] +
                       sX[wslot][k] * sWr[k * CH + lane];
            }
            if (RELU) acc = fmaxf(acc, 0.0f);
            out[(size_t)n * CH + lane] = acc;
        }
        __syncthreads();
    }
}

// ---------------------------------------------------------------------------
// Pair MLP: out[p] = sigmoid( relu([h[a],h[c]] @ Wp1 + bp1) @ Wp2 + bp2 )
// ---------------------------------------------------------------------------
__global__ void pair_mlp(const float* __restrict__ h,
                         const int* __restrict__ p0,
                         const int* __restrict__ p1,
                         const float* __restrict__ Wp1,
                         const float* __restrict__ bp1,
                         const float* __restrict__ Wp2,
                         const float* __restrict__ bp2,
                         float* __restrict__ out) {
    __shared__ float sW1[2 * CH * CH];   // 128 x 64
    __shared__ float sB1[CH];
    __shared__ float sW2[CH];
    __shared__ float sPair[4][2 * CH];

    int tid = threadIdx.x;
    for (int i = tid; i < 2 * CH * CH; i += 256) sW1[i] = Wp1[i];
    if (tid < CH) {
        sB1[tid] = bp1[tid];
        sW2[tid] = Wp2[tid];
    }
    __syncthreads();

    int slot = tid >> 6;
    int lane = tid & 63;
    float b2v = bp2[0];

    for (int q0 = blockIdx.x * 4; q0 < N_PAIRS; q0 += gridDim.x * 4) {
        int q = q0 + slot;
        if (q < N_PAIRS) {
            int a = p0[q];
            int c = p1[q];
            sPair[slot][lane]      = h[(size_t)a * CH + lane];
            sPair[slot][CH + lane] = h[(size_t)c * CH + lane];
        }
        __syncthreads();
        if (q < N_PAIRS) {
            float z = sB1[lane];
#pragma unroll
            for (int i = 0; i < 2 * CH; i++) {
                z += sPair[slot][i] * sW1[i * CH + lane];
            }
            z = fmaxf(z, 0.0f);
            float t = z * sW2[lane];
#pragma unroll
            for (int off = 32; off; off >>= 1) t += __shfl_down(t, off);
            if (lane == 0) {
                float logit = t + b2v;
                out[q] = 1.0f / (1.0f + expf(-logit));
            }
        }
        __syncthreads();
    }
}

// ---------------------------------------------------------------------------
extern "C" void kernel_launch(void* const* d_in, const int* in_sizes, int n_in,
                              void* d_out, int out_size, void* d_ws, size_t ws_size,
                              hipStream_t stream) {
    const float* x   = (const float*)d_in[0];
    const int*   ei  = (const int*)d_in[1];   // [2, E]
    const int*   ep  = (const int*)d_in[2];   // [2, P]
    const float* W1l = (const float*)d_in[3];
    const float* W1r = (const float*)d_in[4];
    const float* b1  = (const float*)d_in[5];
    const float* W2l = (const float*)d_in[6];
    const float* W2r = (const float*)d_in[7];
    const float* b2  = (const float*)d_in[8];
    const float* Wp1 = (const float*)d_in[9];
    const float* bp1 = (const float*)d_in[10];
    const float* Wp2 = (const float*)d_in[11];
    const float* bp2 = (const float*)d_in[12];
    float* out = (float*)d_out;

    const int* e_src = ei;
    const int* e_dst = ei + N_EDGES;
    const int* p_a   = ep;
    const int* p_b   = ep + N_PAIRS;

    // workspace layout (ints then float feature buffers, 16B-aligned)
    int* cnt_i     = (int*)d_ws;                       // N
    int* row_start = cnt_i + N_NODES;                  // N+1
    int* cursor    = row_start + N_NODES + 1;          // N
    int* partial   = cursor + N_NODES;                 // SCAN_NBLK
    int* csr       = (int*)d_ws + 300304;              // E (aligned)
    float* h1      = (float*)d_ws + 300304 + N_EDGES;  // N*CH
    float* h2      = h1 + (size_t)N_NODES * CH;        // N*CH

    // ---- CSR build ----
    hipMemsetAsync(cnt_i, 0, N_NODES * sizeof(int), stream);
    k_hist<<<2048, 256, 0, stream>>>(e_dst, cnt_i);
    k_chunk_sum<<<SCAN_NBLK, 64, 0, stream>>>(cnt_i, partial);
    k_scan_partials<<<1, 64, 0, stream>>>(partial, row_start);
    k_chunk_scan<<<SCAN_NBLK, 64, 0, stream>>>(cnt_i, partial, row_start, cursor);
    k_fill<<<2048, 256, 0, stream>>>(e_src, e_dst, cursor, csr);

    // ---- layers (pull-based, fused agg+transform) ----
    sage_layer<true><<<2048, 256, 0, stream>>>(x, row_start, csr, W1l, W1r, b1, h1);
    sage_layer<false><<<2048, 256, 0, stream>>>(h1, row_start, csr, W2l, W2r, b2, h2);

    // ---- link predictor ----
    pair_mlp<<<2048, 256, 0, stream>>>(h2, p_a, p_b, Wp1, bp1, Wp2, bp2, out);
}

// Round 3
// 549.321 us; speedup vs baseline: 5.7614x; 1.2395x over previous
//
#include <hip/hip_runtime.h>
#include <math.h>

#define N_NODES 100000
#define CH 64
#define N_EDGES 1600000
#define N_PAIRS 200000

#define SCAN_CHUNK 512
#define SCAN_NBLK ((N_NODES + SCAN_CHUNK - 1) / SCAN_CHUNK)   // 196

// ---------------------------------------------------------------------------
// CSR build
// ---------------------------------------------------------------------------
__global__ void k_hist(const int* __restrict__ dst, int* __restrict__ cnt) {
    for (int e = blockIdx.x * blockDim.x + threadIdx.x; e < N_EDGES;
         e += gridDim.x * blockDim.x) {
        atomicAdd(&cnt[dst[e]], 1);
    }
}

__global__ void k_chunk_sum(const int* __restrict__ cnt, int* __restrict__ partial) {
    int b = blockIdx.x;
    int lane = threadIdx.x;            // 64 threads
    int base = b * SCAN_CHUNK;
    int s = 0;
    for (int j = lane; j < SCAN_CHUNK; j += 64) {
        int idx = base + j;
        if (idx < N_NODES) s += cnt[idx];
    }
#pragma unroll
    for (int off = 32; off; off >>= 1) s += __shfl_down(s, off);
    if (lane == 0) partial[b] = s;
}

__global__ void k_scan_partials(int* __restrict__ partial, int* __restrict__ row_start) {
    if (threadIdx.x == 0 && blockIdx.x == 0) {
        int run = 0;
        for (int i = 0; i < SCAN_NBLK; i++) {
            int t = partial[i];
            partial[i] = run;
            run += t;
        }
        row_start[N_NODES] = run;
    }
}

__global__ void k_chunk_scan(const int* __restrict__ cnt, const int* __restrict__ partial,
                             int* __restrict__ row_start, int* __restrict__ cursor) {
    int b = blockIdx.x;
    int lane = threadIdx.x;            // 64 threads
    int base = b * SCAN_CHUNK + lane * 8;
    int v[8];
    int s = 0;
#pragma unroll
    for (int j = 0; j < 8; j++) {
        int idx = base + j;
        v[j] = (idx < N_NODES) ? cnt[idx] : 0;
        s += v[j];
    }
    int incl = s;
#pragma unroll
    for (int off = 1; off < 64; off <<= 1) {
        int t = __shfl_up(incl, off);
        if (lane >= off) incl += t;
    }
    int run = partial[b] + (incl - s);
#pragma unroll
    for (int j = 0; j < 8; j++) {
        int idx = base + j;
        if (idx < N_NODES) { row_start[idx] = run; cursor[idx] = run; }
        run += v[j];
    }
}

__global__ void k_fill(const int* __restrict__ src, const int* __restrict__ dst,
                       int* __restrict__ cursor, int* __restrict__ csr) {
    for (int e = blockIdx.x * blockDim.x + threadIdx.x; e < N_EDGES;
         e += gridDim.x * blockDim.x) {
        int pos = atomicAdd(&cursor[dst[e]], 1);
        csr[pos] = src[e];
    }
}

// ---------------------------------------------------------------------------
// Dense dual GEMM:  outa[n][j] = in[n]·Wa[:,j]
//                   outb[n][j] = in[n]·Wb[:,j] + bias[j]
// Weight column held in 64 VGPRs per thread; input row broadcast from LDS.
// 256 threads = 2 node-slots x 128 output columns. outb may alias `in`
// (row-owner in-place RMW: row staged to LDS before being overwritten).
// ---------------------------------------------------------------------------
__global__ void dual_gemm(const float* __restrict__ in,
                          const float* __restrict__ Wa,
                          const float* __restrict__ Wb,
                          const float* __restrict__ bias,   // applied to outb; may be null
                          float* __restrict__ outa,
                          float* __restrict__ outb) {
    __shared__ float sx[2][CH];
    int tid  = threadIdx.x;
    int half = tid >> 7;        // node slot 0/1
    int j    = tid & 127;       // output column 0..127
    bool isB = (j >= CH);
    int col  = isB ? (j - CH) : j;
    const float* Wcol = (isB ? Wb : Wa) + col;
    float wreg[CH];
#pragma unroll
    for (int k = 0; k < CH; k++) wreg[k] = Wcol[(size_t)k * CH];
    float bv = (isB && bias) ? bias[col] : 0.0f;
    float* outp = isB ? outb : outa;

    for (int n0 = blockIdx.x * 2; n0 < N_NODES; n0 += gridDim.x * 2) {
        if (tid < 128) {
            int nn = n0 + (tid >> 6);
            if (nn < N_NODES) sx[tid >> 6][tid & 63] = in[(size_t)nn * CH + (tid & 63)];
        }
        __syncthreads();
        int n = n0 + half;
        if (n < N_NODES) {
            float acc0 = bv, acc1 = 0.0f;
#pragma unroll
            for (int k4 = 0; k4 < CH / 4; k4 += 2) {
                float4 xv0 = ((const float4*)sx[half])[k4];
                float4 xv1 = ((const float4*)sx[half])[k4 + 1];
                acc0 += xv0.x * wreg[4*k4+0] + xv0.y * wreg[4*k4+1]
                      + xv0.z * wreg[4*k4+2] + xv0.w * wreg[4*k4+3];
                acc1 += xv1.x * wreg[4*k4+4] + xv1.y * wreg[4*k4+5]
                      + xv1.z * wreg[4*k4+6] + xv1.w * wreg[4*k4+7];
            }
            outp[(size_t)n * CH + col] = acc0 + acc1;
        }
        __syncthreads();
    }
}

// ---------------------------------------------------------------------------
// Pure gather-mean + combine (in-place on h):
//   h[n] = act( mean_{s in N(n)} xl[s]  +  h[n] )
// One wave per node: 16 lanes x float4 per neighbor row, 4 neighbors in flight.
// ---------------------------------------------------------------------------
template <bool RELU>
__global__ void gather_mean(const float* __restrict__ xl,
                            const int* __restrict__ row_start,
                            const int* __restrict__ csr,
                            float* __restrict__ h) {
    int tid   = threadIdx.x;
    int wslot = tid >> 6;
    int lane  = tid & 63;
    int grp   = lane >> 4;     // neighbor slot 0..3
    int c4    = lane & 15;     // float4 channel quad

    int n = blockIdx.x * 4 + wslot;
    if (n >= N_NODES) return;
    int beg = row_start[n];
    int end = row_start[n + 1];
    float ax = 0.f, ay = 0.f, az = 0.f, aw = 0.f;
    for (int i = beg + grp; i < end; i += 4) {
        int s = csr[i];
        float4 v = ((const float4*)(xl + (size_t)s * CH))[c4];
        ax += v.x; ay += v.y; az += v.z; aw += v.w;
    }
    ax += __shfl_xor(ax, 16); ay += __shfl_xor(ay, 16);
    az += __shfl_xor(az, 16); aw += __shfl_xor(aw, 16);
    ax += __shfl_xor(ax, 32); ay += __shfl_xor(ay, 32);
    az += __shfl_xor(az, 32); aw += __shfl_xor(aw, 32);
    if (grp == 0) {
        float invc = 1.0f / fmaxf((float)(end - beg), 1.0f);
        float4* hp = (float4*)(h + (size_t)n * CH) + c4;
        float4 r = *hp;
        r.x += ax * invc; r.y += ay * invc; r.z += az * invc; r.w += aw * invc;
        if (RELU) {
            r.x = fmaxf(r.x, 0.f); r.y = fmaxf(r.y, 0.f);
            r.z = fmaxf(r.z, 0.f); r.w = fmaxf(r.w, 0.f);
        }
        *hp = r;
    }
}

// ---------------------------------------------------------------------------
// Pair predictor: out[q] = sigmoid( relu(u[a] + v[b]) · wp2 + bp2 )
// (bp1 pre-folded into u). One wave per pair.
// ---------------------------------------------------------------------------
__global__ void pair_pred(const float* __restrict__ u,
                          const float* __restrict__ v,
                          const int* __restrict__ pa,
                          const int* __restrict__ pb,
                          const float* __restrict__ wp2,
                          const float* __restrict__ bp2,
                          float* __restrict__ out) {
    int tid   = threadIdx.x;
    int wslot = tid >> 6;
    int lane  = tid & 63;
    int q = blockIdx.x * 4 + wslot;
    if (q >= N_PAIRS) return;
    float w2 = wp2[lane];
    int a = pa[q], b = pb[q];
    float z = u[(size_t)a * CH + lane] + v[(size_t)b * CH + lane];
    z = fmaxf(z, 0.f);
    float t = z * w2;
#pragma unroll
    for (int off = 32; off; off >>= 1) t += __shfl_down(t, off);
    if (lane == 0) out[q] = 1.0f / (1.0f + expf(-(t + bp2[0])));
}

// ---------------------------------------------------------------------------
extern "C" void kernel_launch(void* const* d_in, const int* in_sizes, int n_in,
                              void* d_out, int out_size, void* d_ws, size_t ws_size,
                              hipStream_t stream) {
    const float* x   = (const float*)d_in[0];
    const int*   ei  = (const int*)d_in[1];   // [2, E]
    const int*   ep  = (const int*)d_in[2];   // [2, P]
    const float* W1l = (const float*)d_in[3];
    const float* W1r = (const float*)d_in[4];
    const float* b1  = (const float*)d_in[5];
    const float* W2l = (const float*)d_in[6];
    const float* W2r = (const float*)d_in[7];
    const float* b2  = (const float*)d_in[8];
    const float* Wp1 = (const float*)d_in[9];
    const float* bp1 = (const float*)d_in[10];
    const float* Wp2 = (const float*)d_in[11];
    const float* bp2 = (const float*)d_in[12];
    float* out = (float*)d_out;

    const int* e_src = ei;
    const int* e_dst = ei + N_EDGES;
    const int* p_a   = ep;
    const int* p_b   = ep + N_PAIRS;

    // workspace layout
    int* cnt_i     = (int*)d_ws;                        // N
    int* row_start = cnt_i + N_NODES;                   // N+1
    int* cursor    = row_start + N_NODES + 1;           // N
    int* partial   = cursor + N_NODES;                  // SCAN_NBLK
    int* csr       = (int*)d_ws + 300304;               // E (16B aligned)
    float* B1      = (float*)d_ws + 300304 + N_EDGES;   // N*CH
    float* B2      = B1 + (size_t)N_NODES * CH;         // N*CH

    // ---- CSR build ----
    hipMemsetAsync(cnt_i, 0, N_NODES * sizeof(int), stream);
    k_hist<<<2048, 256, 0, stream>>>(e_dst, cnt_i);
    k_chunk_sum<<<SCAN_NBLK, 64, 0, stream>>>(cnt_i, partial);
    k_scan_partials<<<1, 64, 0, stream>>>(partial, row_start);
    k_chunk_scan<<<SCAN_NBLK, 64, 0, stream>>>(cnt_i, partial, row_start, cursor);
    k_fill<<<2048, 256, 0, stream>>>(e_src, e_dst, cursor, csr);

    const int gmean_blocks = (N_NODES + 3) / 4;
    const int pair_blocks  = (N_PAIRS + 3) / 4;

    // ---- layer 1: B1 = x@W1l ; B2 = x@W1r + b1 ; B2 = relu(mean(B1) + B2) ----
    dual_gemm<<<2048, 256, 0, stream>>>(x, W1l, W1r, b1, B1, B2);
    gather_mean<true><<<gmean_blocks, 256, 0, stream>>>(B1, row_start, csr, B2);

    // ---- layer 2 (in-place): B1 = h1@W2l ; B2 = h1@W2r + b2 ; B2 = mean(B1) + B2 ----
    dual_gemm<<<2048, 256, 0, stream>>>(B2, W2l, W2r, b2, B1, B2);
    gather_mean<false><<<gmean_blocks, 256, 0, stream>>>(B1, row_start, csr, B2);

    // ---- pair precompute: B1 = h2@Wp1[64:] (v) ; B2 = h2@Wp1[:64] + bp1 (u) ----
    dual_gemm<<<2048, 256, 0, stream>>>(B2, Wp1 + CH * CH, Wp1, bp1, B1, B2);

    // ---- link predictor ----
    pair_pred<<<pair_blocks, 256, 0, stream>>>(B2, B1, p_a, p_b, Wp2, bp2, out);
}

// Round 4
// 418.954 us; speedup vs baseline: 7.5541x; 1.3112x over previous
//
#include <hip/hip_runtime.h>
#include <math.h>

#define N_NODES 100000
#define CH 64
#define N_EDGES 1600000
#define N_PAIRS 200000

#define SCAN_CHUNK 512
#define SCAN_NBLK ((N_NODES + SCAN_CHUNK - 1) / SCAN_CHUNK)   // 196

#define NB   256      // buckets (contiguous node ranges)
#define NPB  391      // nodes per bucket (256*391 = 100096 >= N)
#define BCAP 7000     // slots per bucket (mean 6250, sd ~79 -> 9.5 sigma)

// ---------------------------------------------------------------------------
// Pass A: bucket edges by dst range into fixed-capacity regions.
// Per-block LDS hist -> one global atomic per bucket -> LDS-cursor scatter.
// ---------------------------------------------------------------------------
__global__ void k_bucketA(const int* __restrict__ src, const int* __restrict__ dst,
                          int* __restrict__ gcur, int2* __restrict__ rec) {
    __shared__ int hist[NB];
    __shared__ int cur[NB];
    int tid = threadIdx.x;              // 256
    hist[tid] = 0;
    __syncthreads();
    int per = (N_EDGES + gridDim.x - 1) / gridDim.x;
    int e0 = blockIdx.x * per;
    int e1 = min(e0 + per, N_EDGES);
    for (int e = e0 + tid; e < e1; e += 256) {
        atomicAdd(&hist[dst[e] / NPB], 1);
    }
    __syncthreads();
    cur[tid] = atomicAdd(&gcur[tid], hist[tid]);   // reserve chunk in bucket
    __syncthreads();
    for (int e = e0 + tid; e < e1; e += 256) {
        int d = dst[e];
        int b = d / NPB;
        int pos = atomicAdd(&cur[b], 1);
        rec[(size_t)b * BCAP + pos] = make_int2(src[e], d);
    }
}

// ---------------------------------------------------------------------------
// Pass B: per-bucket node histogram in LDS -> coalesced cnt write.
// (replaces a 1.6M-global-atomic histogram)
// ---------------------------------------------------------------------------
__global__ void k_bcnt(const int2* __restrict__ rec, const int* __restrict__ gcur,
                       int* __restrict__ cnt) {
    __shared__ int h[NPB];
    int b = blockIdx.x;
    int tid = threadIdx.x;              // 256
    for (int j = tid; j < NPB; j += 256) h[j] = 0;
    __syncthreads();
    int len = gcur[b];
    int n0 = b * NPB;
    const int2* r = rec + (size_t)b * BCAP;
    for (int e = tid; e < len; e += 256) atomicAdd(&h[r[e].y - n0], 1);
    __syncthreads();
    int nmax = min(NPB, N_NODES - n0);
    for (int j = tid; j < nmax; j += 256) cnt[n0 + j] = h[j];
}

// ---------------------------------------------------------------------------
// Scan: cnt -> row_start (exclusive prefix sum over 100k)
// ---------------------------------------------------------------------------
__global__ void k_chunk_sum(const int* __restrict__ cnt, int* __restrict__ partial) {
    int b = blockIdx.x;
    int lane = threadIdx.x;            // 64 threads
    int base = b * SCAN_CHUNK;
    int s = 0;
    for (int j = lane; j < SCAN_CHUNK; j += 64) {
        int idx = base + j;
        if (idx < N_NODES) s += cnt[idx];
    }
#pragma unroll
    for (int off = 32; off; off >>= 1) s += __shfl_down(s, off);
    if (lane == 0) partial[b] = s;
}

__global__ void k_scan_partials(int* __restrict__ partial, int* __restrict__ row_start) {
    if (threadIdx.x == 0 && blockIdx.x == 0) {
        int run = 0;
        for (int i = 0; i < SCAN_NBLK; i++) {
            int t = partial[i];
            partial[i] = run;
            run += t;
        }
        row_start[N_NODES] = run;
    }
}

__global__ void k_chunk_scan(const int* __restrict__ cnt, const int* __restrict__ partial,
                             int* __restrict__ row_start) {
    int b = blockIdx.x;
    int lane = threadIdx.x;            // 64 threads
    int base = b * SCAN_CHUNK + lane * 8;
    int v[8];
    int s = 0;
#pragma unroll
    for (int j = 0; j < 8; j++) {
        int idx = base + j;
        v[j] = (idx < N_NODES) ? cnt[idx] : 0;
        s += v[j];
    }
    int incl = s;
#pragma unroll
    for (int off = 1; off < 64; off <<= 1) {
        int t = __shfl_up(incl, off);
        if (lane >= off) incl += t;
    }
    int run = partial[b] + (incl - s);
#pragma unroll
    for (int j = 0; j < 8; j++) {
        int idx = base + j;
        if (idx < N_NODES) row_start[idx] = run;
        run += v[j];
    }
}

// ---------------------------------------------------------------------------
// Pass C: final placement. LDS cursors seeded from row_start (global ==
// local offsets since counts match). Writes land in a 25KB window per block.
// ---------------------------------------------------------------------------
__global__ void k_place(const int2* __restrict__ rec, const int* __restrict__ gcur,
                        const int* __restrict__ row_start, int* __restrict__ csr) {
    __shared__ int cur[NPB];
    int b = blockIdx.x;
    int tid = threadIdx.x;              // 256
    int n0 = b * NPB;
    int nmax = min(NPB, N_NODES - n0);
    for (int j = tid; j < nmax; j += 256) cur[j] = row_start[n0 + j];
    __syncthreads();
    int len = gcur[b];
    const int2* r = rec + (size_t)b * BCAP;
    for (int e = tid; e < len; e += 256) {
        int2 v = r[e];
        int pos = atomicAdd(&cur[v.y - n0], 1);
        csr[pos] = v.x;
    }
}

// ---------------------------------------------------------------------------
// Dense dual GEMM:  outa[n][j] = in[n]·Wa[:,j] ; outb[n][j] = in[n]·Wb[:,j]+bias[j]
// Weight column in 64 VGPRs/thread; input rows broadcast from LDS.
// outb may alias `in` (row staged to LDS before overwrite).
// ---------------------------------------------------------------------------
__global__ void dual_gemm(const float* __restrict__ in,
                          const float* __restrict__ Wa,
                          const float* __restrict__ Wb,
                          const float* __restrict__ bias,
                          float* __restrict__ outa,
                          float* __restrict__ outb) {
    __shared__ float sx[2][CH];
    int tid  = threadIdx.x;
    int half = tid >> 7;        // node slot 0/1
    int j    = tid & 127;       // output column 0..127
    bool isB = (j >= CH);
    int col  = isB ? (j - CH) : j;
    const float* Wcol = (isB ? Wb : Wa) + col;
    float wreg[CH];
#pragma unroll
    for (int k = 0; k < CH; k++) wreg[k] = Wcol[(size_t)k * CH];
    float bv = (isB && bias) ? bias[col] : 0.0f;
    float* outp = isB ? outb : outa;

    for (int n0 = blockIdx.x * 2; n0 < N_NODES; n0 += gridDim.x * 2) {
        if (tid < 128) {
            int nn = n0 + (tid >> 6);
            if (nn < N_NODES) sx[tid >> 6][tid & 63] = in[(size_t)nn * CH + (tid & 63)];
        }
        __syncthreads();
        int n = n0 + half;
        if (n < N_NODES) {
            float acc0 = bv, acc1 = 0.0f;
#pragma unroll
            for (int k4 = 0; k4 < CH / 4; k4 += 2) {
                float4 xv0 = ((const float4*)sx[half])[k4];
                float4 xv1 = ((const float4*)sx[half])[k4 + 1];
                acc0 += xv0.x * wreg[4*k4+0] + xv0.y * wreg[4*k4+1]
                      + xv0.z * wreg[4*k4+2] + xv0.w * wreg[4*k4+3];
                acc1 += xv1.x * wreg[4*k4+4] + xv1.y * wreg[4*k4+5]
                      + xv1.z * wreg[4*k4+6] + xv1.w * wreg[4*k4+7];
            }
            outp[(size_t)n * CH + col] = acc0 + acc1;
        }
        __syncthreads();
    }
}

// ---------------------------------------------------------------------------
// Gather-mean + combine (in-place):  h[n] = act( mean_{s in N(n)} xl[s] + h[n] )
// ---------------------------------------------------------------------------
template <bool RELU>
__global__ void gather_mean(const float* __restrict__ xl,
                            const int* __restrict__ row_start,
                            const int* __restrict__ csr,
                            float* __restrict__ h) {
    int tid   = threadIdx.x;
    int wslot = tid >> 6;
    int lane  = tid & 63;
    int grp   = lane >> 4;     // neighbor slot 0..3
    int c4    = lane & 15;     // float4 channel quad

    int n = blockIdx.x * 4 + wslot;
    if (n >= N_NODES) return;
    int beg = row_start[n];
    int end = row_start[n + 1];
    float ax = 0.f, ay = 0.f, az = 0.f, aw = 0.f;
    for (int i = beg + grp; i < end; i += 4) {
        int s = csr[i];
        float4 v = ((const float4*)(xl + (size_t)s * CH))[c4];
        ax += v.x; ay += v.y; az += v.z; aw += v.w;
    }
    ax += __shfl_xor(ax, 16); ay += __shfl_xor(ay, 16);
    az += __shfl_xor(az, 16); aw += __shfl_xor(aw, 16);
    ax += __shfl_xor(ax, 32); ay += __shfl_xor(ay, 32);
    az += __shfl_xor(az, 32); aw += __shfl_xor(aw, 32);
    if (grp == 0) {
        float invc = 1.0f / fmaxf((float)(end - beg), 1.0f);
        float4* hp = (float4*)(h + (size_t)n * CH) + c4;
        float4 r = *hp;
        r.x += ax * invc; r.y += ay * invc; r.z += az * invc; r.w += aw * invc;
        if (RELU) {
            r.x = fmaxf(r.x, 0.f); r.y = fmaxf(r.y, 0.f);
            r.z = fmaxf(r.z, 0.f); r.w = fmaxf(r.w, 0.f);
        }
        *hp = r;
    }
}

// ---------------------------------------------------------------------------
// Pair predictor: out[q] = sigmoid( relu(u[a] + v[b]) · wp2 + bp2 )
// ---------------------------------------------------------------------------
__global__ void pair_pred(const float* __restrict__ u,
                          const float* __restrict__ v,
                          const int* __restrict__ pa,
                          const int* __restrict__ pb,
                          const float* __restrict__ wp2,
                          const float* __restrict__ bp2,
                          float* __restrict__ out) {
    int tid   = threadIdx.x;
    int wslot = tid >> 6;
    int lane  = tid & 63;
    int q = blockIdx.x * 4 + wslot;
    if (q >= N_PAIRS) return;
    float w2 = wp2[lane];
    int a = pa[q], b = pb[q];
    float z = u[(size_t)a * CH + lane] + v[(size_t)b * CH + lane];
    z = fmaxf(z, 0.f);
    float t = z * w2;
#pragma unroll
    for (int off = 32; off; off >>= 1) t += __shfl_down(t, off);
    if (lane == 0) out[q] = 1.0f / (1.0f + expf(-(t + bp2[0])));
}

// ---------------------------------------------------------------------------
extern "C" void kernel_launch(void* const* d_in, const int* in_sizes, int n_in,
                              void* d_out, int out_size, void* d_ws, size_t ws_size,
                              hipStream_t stream) {
    const float* x   = (const float*)d_in[0];
    const int*   ei  = (const int*)d_in[1];   // [2, E]
    const int*   ep  = (const int*)d_in[2];   // [2, P]
    const float* W1l = (const float*)d_in[3];
    const float* W1r = (const float*)d_in[4];
    const float* b1  = (const float*)d_in[5];
    const float* W2l = (const float*)d_in[6];
    const float* W2r = (const float*)d_in[7];
    const float* b2  = (const float*)d_in[8];
    const float* Wp1 = (const float*)d_in[9];
    const float* bp1 = (const float*)d_in[10];
    const float* Wp2 = (const float*)d_in[11];
    const float* bp2 = (const float*)d_in[12];
    float* out = (float*)d_out;

    const int* e_src = ei;
    const int* e_dst = ei + N_EDGES;
    const int* p_a   = ep;
    const int* p_b   = ep + N_PAIRS;

    // workspace layout (4B units)
    int* cnt_i     = (int*)d_ws;                        // 100000
    int* row_start = cnt_i + N_NODES;                   // 100001
    int* partial   = row_start + N_NODES + 1;           // 196
    int* gcur      = partial + SCAN_NBLK;               // 256
    int* csr       = (int*)d_ws + 200464;               // E (16B aligned)
    float* B1      = (float*)d_ws + 200464 + N_EDGES;   // N*CH
    float* B2      = B1 + (size_t)N_NODES * CH;         // N*CH
    // rec aliases B1/B2 (dead before first dual_gemm)
    int2* rec      = (int2*)B1;                         // NB*BCAP int2 = 14.3MB

    // ---- CSR build (two-level counting sort) ----
    hipMemsetAsync(gcur, 0, NB * sizeof(int), stream);
    k_bucketA<<<512, NB, 0, stream>>>(e_src, e_dst, gcur, rec);
    k_bcnt<<<NB, 256, 0, stream>>>(rec, gcur, cnt_i);
    k_chunk_sum<<<SCAN_NBLK, 64, 0, stream>>>(cnt_i, partial);
    k_scan_partials<<<1, 64, 0, stream>>>(partial, row_start);
    k_chunk_scan<<<SCAN_NBLK, 64, 0, stream>>>(cnt_i, partial, row_start);
    k_place<<<NB, 256, 0, stream>>>(rec, gcur, row_start, csr);

    const int gmean_blocks = (N_NODES + 3) / 4;
    const int pair_blocks  = (N_PAIRS + 3) / 4;

    // ---- layer 1: B1 = x@W1l ; B2 = x@W1r + b1 ; B2 = relu(mean(B1) + B2) ----
    dual_gemm<<<2048, 256, 0, stream>>>(x, W1l, W1r, b1, B1, B2);
    gather_mean<true><<<gmean_blocks, 256, 0, stream>>>(B1, row_start, csr, B2);

    // ---- layer 2 (in-place): B1 = h1@W2l ; B2 = h1@W2r + b2 ; B2 = mean(B1) + B2 ----
    dual_gemm<<<2048, 256, 0, stream>>>(B2, W2l, W2r, b2, B1, B2);
    gather_mean<false><<<gmean_blocks, 256, 0, stream>>>(B1, row_start, csr, B2);

    // ---- pair precompute: B1 = h2@Wp1[64:] (v) ; B2 = h2@Wp1[:64] + bp1 (u) ----
    dual_gemm<<<2048, 256, 0, stream>>>(B2, Wp1 + CH * CH, Wp1, bp1, B1, B2);

    // ---- link predictor ----
    pair_pred<<<pair_blocks, 256, 0, stream>>>(B2, B1, p_a, p_b, Wp2, bp2, out);
}

// Round 5
// 345.492 us; speedup vs baseline: 9.1604x; 1.2126x over previous
//
#include <hip/hip_runtime.h>
#include <math.h>

#define N_NODES 100000
#define CH 64
#define N_EDGES 1600000
#define N_PAIRS 200000

#define SCAN_CHUNK 512
#define SCAN_NBLK ((N_NODES + SCAN_CHUNK - 1) / SCAN_CHUNK)   // 196

#define NB   256      // buckets (contiguous node ranges)
#define NPB  391      // nodes per bucket (256*391 = 100096 >= N)
#define BCAP 7000     // slots per bucket (mean 6250, sd ~79)

typedef unsigned short ushort_t;
typedef unsigned int   uint_t;

// ---- bf16 helpers (RNE) ----------------------------------------------------
__device__ __forceinline__ float bf2f(uint_t u) {
    union { uint_t u; float f; } c; c.u = u << 16; return c.f;
}
__device__ __forceinline__ uint_t f2bf(float f) {
    union { float f; uint_t u; } c; c.f = f;
    return (c.u + 0x7FFFu + ((c.u >> 16) & 1u)) >> 16;
}
__device__ __forceinline__ uint_t pack2(float lo, float hi) {
    return f2bf(lo) | (f2bf(hi) << 16);
}

// ---------------------------------------------------------------------------
// CSR build, pass A: bucket edges by dst range. Packed record: src<<9 | local
// ---------------------------------------------------------------------------
__global__ void k_bucketA(const int* __restrict__ src, const int* __restrict__ dst,
                          int* __restrict__ gcur, uint_t* __restrict__ rec) {
    __shared__ int hist[NB];
    __shared__ int cur[NB];
    int tid = threadIdx.x;              // 256
    hist[tid] = 0;
    __syncthreads();
    int per = (N_EDGES + gridDim.x - 1) / gridDim.x;
    int e0 = blockIdx.x * per;
    int e1 = min(e0 + per, N_EDGES);
    for (int e = e0 + tid; e < e1; e += 256) {
        atomicAdd(&hist[dst[e] / NPB], 1);
    }
    __syncthreads();
    cur[tid] = atomicAdd(&gcur[tid], hist[tid]);
    __syncthreads();
    for (int e = e0 + tid; e < e1; e += 256) {
        int d = dst[e];
        int b = d / NPB;
        int pos = atomicAdd(&cur[b], 1);
        rec[(size_t)b * BCAP + pos] = ((uint_t)src[e] << 9) | (uint_t)(d - b * NPB);
    }
}

// Pass B: per-bucket node histogram in LDS -> coalesced cnt write
__global__ void k_bcnt(const uint_t* __restrict__ rec, const int* __restrict__ gcur,
                       int* __restrict__ cnt) {
    __shared__ int h[NPB];
    int b = blockIdx.x;
    int tid = threadIdx.x;              // 256
    for (int j = tid; j < NPB; j += 256) h[j] = 0;
    __syncthreads();
    int len = gcur[b];
    int n0 = b * NPB;
    const uint_t* r = rec + (size_t)b * BCAP;
    for (int e = tid; e < len; e += 256) atomicAdd(&h[r[e] & 511u], 1);
    __syncthreads();
    int nmax = min(NPB, N_NODES - n0);
    for (int j = tid; j < nmax; j += 256) cnt[n0 + j] = h[j];
}

// Scan: cnt -> row_start
__global__ void k_chunk_sum(const int* __restrict__ cnt, int* __restrict__ partial) {
    int b = blockIdx.x;
    int lane = threadIdx.x;            // 64
    int base = b * SCAN_CHUNK;
    int s = 0;
    for (int j = lane; j < SCAN_CHUNK; j += 64) {
        int idx = base + j;
        if (idx < N_NODES) s += cnt[idx];
    }
#pragma unroll
    for (int off = 32; off; off >>= 1) s += __shfl_down(s, off);
    if (lane == 0) partial[b] = s;
}

__global__ void k_scan_partials(int* __restrict__ partial, int* __restrict__ row_start) {
    if (threadIdx.x == 0 && blockIdx.x == 0) {
        int run = 0;
        for (int i = 0; i < SCAN_NBLK; i++) {
            int t = partial[i];
            partial[i] = run;
            run += t;
        }
        row_start[N_NODES] = run;
    }
}

__global__ void k_chunk_scan(const int* __restrict__ cnt, const int* __restrict__ partial,
                             int* __restrict__ row_start) {
    int b = blockIdx.x;
    int lane = threadIdx.x;            // 64
    int base = b * SCAN_CHUNK + lane * 8;
    int v[8];
    int s = 0;
#pragma unroll
    for (int j = 0; j < 8; j++) {
        int idx = base + j;
        v[j] = (idx < N_NODES) ? cnt[idx] : 0;
        s += v[j];
    }
    int incl = s;
#pragma unroll
    for (int off = 1; off < 64; off <<= 1) {
        int t = __shfl_up(incl, off);
        if (lane >= off) incl += t;
    }
    int run = partial[b] + (incl - s);
#pragma unroll
    for (int j = 0; j < 8; j++) {
        int idx = base + j;
        if (idx < N_NODES) row_start[idx] = run;
        run += v[j];
    }
}

// Pass C: final placement (LDS cursors; ~25KB write window per block)
__global__ void k_place(const uint_t* __restrict__ rec, const int* __restrict__ gcur,
                        const int* __restrict__ row_start, int* __restrict__ csr) {
    __shared__ int cur[NPB];
    int b = blockIdx.x;
    int tid = threadIdx.x;              // 256
    int n0 = b * NPB;
    int nmax = min(NPB, N_NODES - n0);
    for (int j = tid; j < nmax; j += 256) cur[j] = row_start[n0 + j];
    __syncthreads();
    int len = gcur[b];
    const uint_t* r = rec + (size_t)b * BCAP;
    for (int e = tid; e < len; e += 256) {
        uint_t v = r[e];
        int pos = atomicAdd(&cur[v & 511u], 1);
        csr[pos] = (int)(v >> 9);
    }
}

// ---------------------------------------------------------------------------
// Dense dual GEMM (bf16 out):  outa[n][j] = in[n]·Wa[:,j]
//                              outb[n][j] = in[n]·Wb[:,j] + bias[j]
// Weight col in 64 VGPRs/thread; rows broadcast from LDS. outb may alias in.
// ---------------------------------------------------------------------------
__device__ __forceinline__ float ldf(const float* p, size_t i)    { return p[i]; }
__device__ __forceinline__ float ldf(const ushort_t* p, size_t i) { return bf2f(p[i]); }

template <typename TIN>
__global__ void dual_gemm(const TIN* __restrict__ in,
                          const float* __restrict__ Wa,
                          const float* __restrict__ Wb,
                          const float* __restrict__ bias,
                          ushort_t* __restrict__ outa,
                          ushort_t* __restrict__ outb) {
    __shared__ float sx[2][CH];
    int tid  = threadIdx.x;
    int half = tid >> 7;        // node slot 0/1
    int j    = tid & 127;       // output column 0..127
    bool isB = (j >= CH);
    int col  = isB ? (j - CH) : j;
    const float* Wcol = (isB ? Wb : Wa) + col;
    float wreg[CH];
#pragma unroll
    for (int k = 0; k < CH; k++) wreg[k] = Wcol[(size_t)k * CH];
    float bv = (isB && bias) ? bias[col] : 0.0f;
    ushort_t* outp = isB ? outb : outa;

    for (int n0 = blockIdx.x * 2; n0 < N_NODES; n0 += gridDim.x * 2) {
        if (tid < 128) {
            int nn = n0 + (tid >> 6);
            if (nn < N_NODES)
                sx[tid >> 6][tid & 63] = ldf(in, (size_t)nn * CH + (tid & 63));
        }
        __syncthreads();
        int n = n0 + half;
        if (n < N_NODES) {
            float acc0 = bv, acc1 = 0.0f;
#pragma unroll
            for (int k4 = 0; k4 < CH / 4; k4 += 2) {
                float4 xv0 = ((const float4*)sx[half])[k4];
                float4 xv1 = ((const float4*)sx[half])[k4 + 1];
                acc0 += xv0.x * wreg[4*k4+0] + xv0.y * wreg[4*k4+1]
                      + xv0.z * wreg[4*k4+2] + xv0.w * wreg[4*k4+3];
                acc1 += xv1.x * wreg[4*k4+4] + xv1.y * wreg[4*k4+5]
                      + xv1.z * wreg[4*k4+6] + xv1.w * wreg[4*k4+7];
            }
            outp[(size_t)n * CH + col] = (ushort_t)f2bf(acc0 + acc1);
        }
        __syncthreads();
    }
}

// ---------------------------------------------------------------------------
// Gather-mean + combine (in-place, bf16):
//   h[n] = act( mean_{s in N(n)} xl[s] + h[n] )
// One wave/node: 8 lanes x uint4(8 bf16) per row, 8 neighbors in flight.
// ---------------------------------------------------------------------------
template <bool RELU>
__global__ void gather_mean(const ushort_t* __restrict__ xl,
                            const int* __restrict__ row_start,
                            const int* __restrict__ csr,
                            ushort_t* __restrict__ h) {
    int tid   = threadIdx.x;
    int wslot = tid >> 6;
    int lane  = tid & 63;
    int grp   = lane >> 3;     // neighbor slot 0..7
    int c8    = lane & 7;      // 8-bf16 chunk index

    int n = blockIdx.x * 4 + wslot;
    if (n >= N_NODES) return;
    int beg = row_start[n];
    int end = row_start[n + 1];
    float a[8];
#pragma unroll
    for (int j = 0; j < 8; j++) a[j] = 0.0f;
    for (int i = beg + grp; i < end; i += 8) {
        int s = csr[i];
        uint4 v = ((const uint4*)(xl + (size_t)s * CH))[c8];
        a[0] += bf2f(v.x & 0xffffu); a[1] += bf2f(v.x >> 16);
        a[2] += bf2f(v.y & 0xffffu); a[3] += bf2f(v.y >> 16);
        a[4] += bf2f(v.z & 0xffffu); a[5] += bf2f(v.z >> 16);
        a[6] += bf2f(v.w & 0xffffu); a[7] += bf2f(v.w >> 16);
    }
#pragma unroll
    for (int off = 8; off <= 32; off <<= 1) {
#pragma unroll
        for (int j = 0; j < 8; j++) a[j] += __shfl_xor(a[j], off);
    }
    if (grp == 0) {
        float invc = 1.0f / fmaxf((float)(end - beg), 1.0f);
        uint4* hp = (uint4*)(h + (size_t)n * CH) + c8;
        uint4 r = *hp;
        float f0 = bf2f(r.x & 0xffffu) + a[0] * invc;
        float f1 = bf2f(r.x >> 16)     + a[1] * invc;
        float f2 = bf2f(r.y & 0xffffu) + a[2] * invc;
        float f3 = bf2f(r.y >> 16)     + a[3] * invc;
        float f4 = bf2f(r.z & 0xffffu) + a[4] * invc;
        float f5 = bf2f(r.z >> 16)     + a[5] * invc;
        float f6 = bf2f(r.w & 0xffffu) + a[6] * invc;
        float f7 = bf2f(r.w >> 16)     + a[7] * invc;
        if (RELU) {
            f0 = fmaxf(f0, 0.f); f1 = fmaxf(f1, 0.f);
            f2 = fmaxf(f2, 0.f); f3 = fmaxf(f3, 0.f);
            f4 = fmaxf(f4, 0.f); f5 = fmaxf(f5, 0.f);
            f6 = fmaxf(f6, 0.f); f7 = fmaxf(f7, 0.f);
        }
        *hp = make_uint4(pack2(f0, f1), pack2(f2, f3), pack2(f4, f5), pack2(f6, f7));
    }
}

// ---------------------------------------------------------------------------
// Pair predictor: out[q] = sigmoid( relu(u[a] + v[b]) · wp2 + bp2 )
// 32 lanes per pair; lane handles 2 channels (uint = 2 bf16).
// ---------------------------------------------------------------------------
__global__ void pair_pred(const ushort_t* __restrict__ u,
                          const ushort_t* __restrict__ v,
                          const int* __restrict__ pa,
                          const int* __restrict__ pb,
                          const float* __restrict__ wp2,
                          const float* __restrict__ bp2,
                          float* __restrict__ out) {
    int tid = threadIdx.x;
    int q   = blockIdx.x * 8 + (tid >> 5);
    int hl  = tid & 31;
    if (q >= N_PAIRS) return;
    int a = pa[q], b = pb[q];
    uint_t uu = ((const uint_t*)u)[(size_t)a * 32 + hl];
    uint_t vv = ((const uint_t*)v)[(size_t)b * 32 + hl];
    float2 w2 = ((const float2*)wp2)[hl];
    float z0 = fmaxf(bf2f(uu & 0xffffu) + bf2f(vv & 0xffffu), 0.f);
    float z1 = fmaxf(bf2f(uu >> 16) + bf2f(vv >> 16), 0.f);
    float t = z0 * w2.x + z1 * w2.y;
#pragma unroll
    for (int off = 1; off <= 16; off <<= 1) t += __shfl_xor(t, off);
    if (hl == 0) out[q] = 1.0f / (1.0f + expf(-(t + bp2[0])));
}

// ---------------------------------------------------------------------------
extern "C" void kernel_launch(void* const* d_in, const int* in_sizes, int n_in,
                              void* d_out, int out_size, void* d_ws, size_t ws_size,
                              hipStream_t stream) {
    const float* x   = (const float*)d_in[0];
    const int*   ei  = (const int*)d_in[1];   // [2, E]
    const int*   ep  = (const int*)d_in[2];   // [2, P]
    const float* W1l = (const float*)d_in[3];
    const float* W1r = (const float*)d_in[4];
    const float* b1  = (const float*)d_in[5];
    const float* W2l = (const float*)d_in[6];
    const float* W2r = (const float*)d_in[7];
    const float* b2  = (const float*)d_in[8];
    const float* Wp1 = (const float*)d_in[9];
    const float* bp1 = (const float*)d_in[10];
    const float* Wp2 = (const float*)d_in[11];
    const float* bp2 = (const float*)d_in[12];
    float* out = (float*)d_out;

    const int* e_src = ei;
    const int* e_dst = ei + N_EDGES;
    const int* p_a   = ep;
    const int* p_b   = ep + N_PAIRS;

    // workspace layout (4B word units)
    int* cnt_i     = (int*)d_ws;                        // 100000
    int* row_start = cnt_i + N_NODES;                   // 100001
    int* partial   = row_start + N_NODES + 1;           // 196
    int* gcur      = partial + SCAN_NBLK;               // 256
    int* csr       = (int*)d_ws + 200464;               // E words (16B aligned)
    ushort_t* B1   = (ushort_t*)((int*)d_ws + 200464 + N_EDGES);  // N*CH bf16
    ushort_t* B2   = B1 + (size_t)N_NODES * CH;                   // N*CH bf16
    uint_t* rec    = (uint_t*)B1;   // NB*BCAP uints = 7.2MB, dead before GEMMs

    // ---- CSR build (two-level counting sort, packed records) ----
    hipMemsetAsync(gcur, 0, NB * sizeof(int), stream);
    k_bucketA<<<512, NB, 0, stream>>>(e_src, e_dst, gcur, rec);
    k_bcnt<<<NB, 256, 0, stream>>>(rec, gcur, cnt_i);
    k_chunk_sum<<<SCAN_NBLK, 64, 0, stream>>>(cnt_i, partial);
    k_scan_partials<<<1, 64, 0, stream>>>(partial, row_start);
    k_chunk_scan<<<SCAN_NBLK, 64, 0, stream>>>(cnt_i, partial, row_start);
    k_place<<<NB, 256, 0, stream>>>(rec, gcur, row_start, csr);

    const int gmean_blocks = (N_NODES + 3) / 4;
    const int pair_blocks  = (N_PAIRS + 7) / 8;

    // ---- layer 1: B1 = x@W1l ; B2 = x@W1r + b1 ; B2 = relu(mean(B1)+B2) ----
    dual_gemm<float><<<2048, 256, 0, stream>>>(x, W1l, W1r, b1, B1, B2);
    gather_mean<true><<<gmean_blocks, 256, 0, stream>>>(B1, row_start, csr, B2);

    // ---- layer 2 (in-place): B1 = h1@W2l ; B2 = h1@W2r + b2 ; combine ----
    dual_gemm<ushort_t><<<2048, 256, 0, stream>>>(B2, W2l, W2r, b2, B1, B2);
    gather_mean<false><<<gmean_blocks, 256, 0, stream>>>(B1, row_start, csr, B2);

    // ---- pair precompute: B1 = h2@Wp1[64:] (v) ; B2 = h2@Wp1[:64]+bp1 (u) ----
    dual_gemm<ushort_t><<<2048, 256, 0, stream>>>(B2, Wp1 + CH * CH, Wp1, bp1, B1, B2);

    // ---- link predictor ----
    pair_pred<<<pair_blocks, 256, 0, stream>>>(B2, B1, p_a, p_b, Wp2, bp2, out);
}

// Round 6
// 249.062 us; speedup vs baseline: 12.7070x; 1.3872x over previous
//
#include <hip/hip_runtime.h>
#include <math.h>

#define N_NODES 100000
#define CH 64
#define N_EDGES 1600000
#define N_PAIRS 200000

#define SCAN_CHUNK 512
#define SCAN_NBLK ((N_NODES + SCAN_CHUNK - 1) / SCAN_CHUNK)   // 196

#define NB   256      // buckets (contiguous node ranges)
#define NPB  391      // nodes per bucket (256*391 = 100096 >= N)
#define BCAP 7000     // slots per bucket (mean 6250, sd ~79)

typedef unsigned short ushort_t;
typedef unsigned int   uint_t;
typedef __attribute__((ext_vector_type(8))) short short8_t;   // 8 bf16 = 4 VGPR
typedef __attribute__((ext_vector_type(4))) short short4_t;   // 4 bf16 = 8B
typedef __attribute__((ext_vector_type(4))) float f32x4;      // MFMA acc

// ---- bf16 helpers (RNE) ----------------------------------------------------
__device__ __forceinline__ float bf2f(uint_t u) {
    union { uint_t u; float f; } c; c.u = u << 16; return c.f;
}
__device__ __forceinline__ uint_t f2bf(float f) {
    union { float f; uint_t u; } c; c.f = f;
    return (c.u + 0x7FFFu + ((c.u >> 16) & 1u)) >> 16;
}
__device__ __forceinline__ uint_t pack2(float lo, float hi) {
    return f2bf(lo) | (f2bf(hi) << 16);
}

// ---------------------------------------------------------------------------
// CSR build, pass A: bucket edges by dst range. Packed record: src<<9 | local
// ---------------------------------------------------------------------------
__global__ void k_bucketA(const int* __restrict__ src, const int* __restrict__ dst,
                          int* __restrict__ gcur, uint_t* __restrict__ rec) {
    __shared__ int hist[NB];
    __shared__ int cur[NB];
    int tid = threadIdx.x;              // 256
    hist[tid] = 0;
    __syncthreads();
    int per = (N_EDGES + gridDim.x - 1) / gridDim.x;
    int e0 = blockIdx.x * per;
    int e1 = min(e0 + per, N_EDGES);
    for (int e = e0 + tid; e < e1; e += 256) {
        atomicAdd(&hist[dst[e] / NPB], 1);
    }
    __syncthreads();
    cur[tid] = atomicAdd(&gcur[tid], hist[tid]);
    __syncthreads();
    for (int e = e0 + tid; e < e1; e += 256) {
        int d = dst[e];
        int b = d / NPB;
        int pos = atomicAdd(&cur[b], 1);
        rec[(size_t)b * BCAP + pos] = ((uint_t)src[e] << 9) | (uint_t)(d - b * NPB);
    }
}

// Pass B: per-bucket node histogram in LDS -> coalesced cnt write
__global__ void k_bcnt(const uint_t* __restrict__ rec, const int* __restrict__ gcur,
                       int* __restrict__ cnt) {
    __shared__ int h[NPB];
    int b = blockIdx.x;
    int tid = threadIdx.x;              // 256
    for (int j = tid; j < NPB; j += 256) h[j] = 0;
    __syncthreads();
    int len = gcur[b];
    int n0 = b * NPB;
    const uint_t* r = rec + (size_t)b * BCAP;
    for (int e = tid; e < len; e += 256) atomicAdd(&h[r[e] & 511u], 1);
    __syncthreads();
    int nmax = min(NPB, N_NODES - n0);
    for (int j = tid; j < nmax; j += 256) cnt[n0 + j] = h[j];
}

// Scan: cnt -> row_start
__global__ void k_chunk_sum(const int* __restrict__ cnt, int* __restrict__ partial) {
    int b = blockIdx.x;
    int lane = threadIdx.x;            // 64
    int base = b * SCAN_CHUNK;
    int s = 0;
    for (int j = lane; j < SCAN_CHUNK; j += 64) {
        int idx = base + j;
        if (idx < N_NODES) s += cnt[idx];
    }
#pragma unroll
    for (int off = 32; off; off >>= 1) s += __shfl_down(s, off);
    if (lane == 0) partial[b] = s;
}

__global__ void k_scan_partials(int* __restrict__ partial, int* __restrict__ row_start) {
    if (threadIdx.x == 0 && blockIdx.x == 0) {
        int run = 0;
        for (int i = 0; i < SCAN_NBLK; i++) {
            int t = partial[i];
            partial[i] = run;
            run += t;
        }
        row_start[N_NODES] = run;
    }
}

__global__ void k_chunk_scan(const int* __restrict__ cnt, const int* __restrict__ partial,
                             int* __restrict__ row_start) {
    int b = blockIdx.x;
    int lane = threadIdx.x;            // 64
    int base = b * SCAN_CHUNK + lane * 8;
    int v[8];
    int s = 0;
#pragma unroll
    for (int j = 0; j < 8; j++) {
        int idx = base + j;
        v[j] = (idx < N_NODES) ? cnt[idx] : 0;
        s += v[j];
    }
    int incl = s;
#pragma unroll
    for (int off = 1; off < 64; off <<= 1) {
        int t = __shfl_up(incl, off);
        if (lane >= off) incl += t;
    }
    int run = partial[b] + (incl - s);
#pragma unroll
    for (int j = 0; j < 8; j++) {
        int idx = base + j;
        if (idx < N_NODES) row_start[idx] = run;
        run += v[j];
    }
}

// Pass C: final placement (LDS cursors; ~25KB write window per block)
__global__ void k_place(const uint_t* __restrict__ rec, const int* __restrict__ gcur,
                        const int* __restrict__ row_start, int* __restrict__ csr) {
    __shared__ int cur[NPB];
    int b = blockIdx.x;
    int tid = threadIdx.x;              // 256
    int n0 = b * NPB;
    int nmax = min(NPB, N_NODES - n0);
    for (int j = tid; j < nmax; j += 256) cur[j] = row_start[n0 + j];
    __syncthreads();
    int len = gcur[b];
    const uint_t* r = rec + (size_t)b * BCAP;
    for (int e = tid; e < len; e += 256) {
        uint_t v = r[e];
        int pos = atomicAdd(&cur[v & 511u], 1);
        csr[pos] = (int)(v >> 9);
    }
}

// ---------------------------------------------------------------------------
// MFMA dual GEMM:  outa[n][j] = in[n]·Wa[:,j] ; outb[n][j] = in[n]·Wb[:,j]+bias[j]
// 16x16x32 bf16 MFMA, SWAPPED operands (A = weights, B = activations) so each
// lane's 4 acc regs are 4 consecutive output channels of one node -> 8B store.
// Weights preloaded once into 64 VGPRs of A-fragments; bias folded into acc
// init. One wave per 16-node tile, grid-stride. outb may alias `in` (each
// row is read and written only by its owning wave, load precedes store).
// ---------------------------------------------------------------------------
__device__ __forceinline__ short8_t load_bfrag(const ushort_t* in, size_t off) {
    return *(const short8_t*)(in + off);           // 16B aligned
}
__device__ __forceinline__ short8_t load_bfrag(const float* in, size_t off) {
    float4 f0 = ((const float4*)(in + off))[0];
    float4 f1 = ((const float4*)(in + off))[1];
    short8_t r;
    r[0] = (short)f2bf(f0.x); r[1] = (short)f2bf(f0.y);
    r[2] = (short)f2bf(f0.z); r[3] = (short)f2bf(f0.w);
    r[4] = (short)f2bf(f1.x); r[5] = (short)f2bf(f1.y);
    r[6] = (short)f2bf(f1.z); r[7] = (short)f2bf(f1.w);
    return r;
}

template <typename TIN>
__global__ __launch_bounds__(256, 2)
void mfma_dual_gemm(const TIN* __restrict__ in,
                    const float* __restrict__ Wa,
                    const float* __restrict__ Wb,
                    const float* __restrict__ bias,
                    ushort_t* __restrict__ outa,
                    ushort_t* __restrict__ outb) {
    int lane = threadIdx.x & 63;
    int wid  = threadIdx.x >> 6;
    int r16  = lane & 15;      // node-within-tile (B col / D col)
    int g    = lane >> 4;      // k-group 0..3

    // Preload weight A-fragments: afrag[c][h]; c = col-tile (0..3 Wa, 4..7 Wb),
    // h = K-half. A[m][k]: m(row)=r16 -> output col (c&3)*16+r16; k = 32h+8g+j.
    short8_t afrag[8][2];
#pragma unroll
    for (int c = 0; c < 8; c++) {
        const float* W = (c < 4) ? Wa : Wb;
        int col = (c & 3) * 16 + r16;
#pragma unroll
        for (int h = 0; h < 2; h++) {
            short8_t a;
#pragma unroll
            for (int j = 0; j < 8; j++)
                a[j] = (short)f2bf(W[(size_t)(32 * h + 8 * g + j) * CH + col]);
            afrag[c][h] = a;
        }
    }
    // Bias folded into accumulator init. D row r (reg) = output col (c&3)*16+g*4+r.
    f32x4 binit[8];
#pragma unroll
    for (int c = 0; c < 8; c++) {
#pragma unroll
        for (int r = 0; r < 4; r++)
            binit[c][r] = (c >= 4 && bias) ? bias[(c & 3) * 16 + g * 4 + r] : 0.0f;
    }

    const int NT = N_NODES / 16;     // 6250 node tiles
    for (int t = blockIdx.x * 4 + wid; t < NT; t += gridDim.x * 4) {
        int n = t * 16 + r16;
        size_t rowoff = (size_t)n * CH;
        // B[k][node]: node=r16, k=32h+8g+j -> 16B contiguous per lane per half
        short8_t b0 = load_bfrag(in, rowoff + 8 * g);
        short8_t b1 = load_bfrag(in, rowoff + 32 + 8 * g);
#pragma unroll
        for (int c = 0; c < 8; c++) {
            f32x4 acc = __builtin_amdgcn_mfma_f32_16x16x32_bf16(
                            afrag[c][0], b0, binit[c], 0, 0, 0);
            acc = __builtin_amdgcn_mfma_f32_16x16x32_bf16(
                            afrag[c][1], b1, acc, 0, 0, 0);
            ushort_t* outp = (c < 4) ? outa : outb;
            short4_t o;
            o[0] = (short)f2bf(acc[0]); o[1] = (short)f2bf(acc[1]);
            o[2] = (short)f2bf(acc[2]); o[3] = (short)f2bf(acc[3]);
            *(short4_t*)(outp + rowoff + (c & 3) * 16 + g * 4) = o;
        }
    }
}

// ---------------------------------------------------------------------------
// Gather-mean + combine (in-place, bf16):
//   h[n] = act( mean_{s in N(n)} xl[s] + h[n] )
// One wave/node: 8 lanes x uint4(8 bf16) per row, 8 neighbors in flight.
// ---------------------------------------------------------------------------
template <bool RELU>
__global__ void gather_mean(const ushort_t* __restrict__ xl,
                            const int* __restrict__ row_start,
                            const int* __restrict__ csr,
                            ushort_t* __restrict__ h) {
    int tid   = threadIdx.x;
    int wslot = tid >> 6;
    int lane  = tid & 63;
    int grp   = lane >> 3;     // neighbor slot 0..7
    int c8    = lane & 7;      // 8-bf16 chunk index

    int n = blockIdx.x * 4 + wslot;
    if (n >= N_NODES) return;
    int beg = row_start[n];
    int end = row_start[n + 1];
    float a[8];
#pragma unroll
    for (int j = 0; j < 8; j++) a[j] = 0.0f;
    for (int i = beg + grp; i < end; i += 8) {
        int s = csr[i];
        uint4 v = ((const uint4*)(xl + (size_t)s * CH))[c8];
        a[0] += bf2f(v.x & 0xffffu); a[1] += bf2f(v.x >> 16);
        a[2] += bf2f(v.y & 0xffffu); a[3] += bf2f(v.y >> 16);
        a[4] += bf2f(v.z & 0xffffu); a[5] += bf2f(v.z >> 16);
        a[6] += bf2f(v.w & 0xffffu); a[7] += bf2f(v.w >> 16);
    }
#pragma unroll
    for (int off = 8; off <= 32; off <<= 1) {
#pragma unroll
        for (int j = 0; j < 8; j++) a[j] += __shfl_xor(a[j], off);
    }
    if (grp == 0) {
        float invc = 1.0f / fmaxf((float)(end - beg), 1.0f);
        uint4* hp = (uint4*)(h + (size_t)n * CH) + c8;
        uint4 r = *hp;
        float f0 = bf2f(r.x & 0xffffu) + a[0] * invc;
        float f1 = bf2f(r.x >> 16)     + a[1] * invc;
        float f2 = bf2f(r.y & 0xffffu) + a[2] * invc;
        float f3 = bf2f(r.y >> 16)     + a[3] * invc;
        float f4 = bf2f(r.z & 0xffffu) + a[4] * invc;
        float f5 = bf2f(r.z >> 16)     + a[5] * invc;
        float f6 = bf2f(r.w & 0xffffu) + a[6] * invc;
        float f7 = bf2f(r.w >> 16)     + a[7] * invc;
        if (RELU) {
            f0 = fmaxf(f0, 0.f); f1 = fmaxf(f1, 0.f);
            f2 = fmaxf(f2, 0.f); f3 = fmaxf(f3, 0.f);
            f4 = fmaxf(f4, 0.f); f5 = fmaxf(f5, 0.f);
            f6 = fmaxf(f6, 0.f); f7 = fmaxf(f7, 0.f);
        }
        *hp = make_uint4(pack2(f0, f1), pack2(f2, f3), pack2(f4, f5), pack2(f6, f7));
    }
}

// ---------------------------------------------------------------------------
// Pair predictor: out[q] = sigmoid( relu(u[a] + v[b]) · wp2 + bp2 )
// 32 lanes per pair; lane handles 2 channels (uint = 2 bf16).
// ---------------------------------------------------------------------------
__global__ void pair_pred(const ushort_t* __restrict__ u,
                          const ushort_t* __restrict__ v,
                          const int* __restrict__ pa,
                          const int* __restrict__ pb,
                          const float* __restrict__ wp2,
                          const float* __restrict__ bp2,
                          float* __restrict__ out) {
    int tid = threadIdx.x;
    int q   = blockIdx.x * 8 + (tid >> 5);
    int hl  = tid & 31;
    if (q >= N_PAIRS) return;
    int a = pa[q], b = pb[q];
    uint_t uu = ((const uint_t*)u)[(size_t)a * 32 + hl];
    uint_t vv = ((const uint_t*)v)[(size_t)b * 32 + hl];
    float2 w2 = ((const float2*)wp2)[hl];
    float z0 = fmaxf(bf2f(uu & 0xffffu) + bf2f(vv & 0xffffu), 0.f);
    float z1 = fmaxf(bf2f(uu >> 16) + bf2f(vv >> 16), 0.f);
    float t = z0 * w2.x + z1 * w2.y;
#pragma unroll
    for (int off = 1; off <= 16; off <<= 1) t += __shfl_xor(t, off);
    if (hl == 0) out[q] = 1.0f / (1.0f + expf(-(t + bp2[0])));
}

// ---------------------------------------------------------------------------
extern "C" void kernel_launch(void* const* d_in, const int* in_sizes, int n_in,
                              void* d_out, int out_size, void* d_ws, size_t ws_size,
                              hipStream_t stream) {
    const float* x   = (const float*)d_in[0];
    const int*   ei  = (const int*)d_in[1];   // [2, E]
    const int*   ep  = (const int*)d_in[2];   // [2, P]
    const float* W1l = (const float*)d_in[3];
    const float* W1r = (const float*)d_in[4];
    const float* b1  = (const float*)d_in[5];
    const float* W2l = (const float*)d_in[6];
    const float* W2r = (const float*)d_in[7];
    const float* b2  = (const float*)d_in[8];
    const float* Wp1 = (const float*)d_in[9];
    const float* bp1 = (const float*)d_in[10];
    const float* Wp2 = (const float*)d_in[11];
    const float* bp2 = (const float*)d_in[12];
    float* out = (float*)d_out;

    const int* e_src = ei;
    const int* e_dst = ei + N_EDGES;
    const int* p_a   = ep;
    const int* p_b   = ep + N_PAIRS;

    // workspace layout (4B word units)
    int* cnt_i     = (int*)d_ws;                        // 100000
    int* row_start = cnt_i + N_NODES;                   // 100001
    int* partial   = row_start + N_NODES + 1;           // 196
    int* gcur      = partial + SCAN_NBLK;               // 256
    int* csr       = (int*)d_ws + 200464;               // E words (16B aligned)
    ushort_t* B1   = (ushort_t*)((int*)d_ws + 200464 + N_EDGES);  // N*CH bf16
    ushort_t* B2   = B1 + (size_t)N_NODES * CH;                   // N*CH bf16
    uint_t* rec    = (uint_t*)B1;   // NB*BCAP uints = 7.2MB, dead before GEMMs

    // ---- CSR build (two-level counting sort, packed records) ----
    hipMemsetAsync(gcur, 0, NB * sizeof(int), stream);
    k_bucketA<<<512, NB, 0, stream>>>(e_src, e_dst, gcur, rec);
    k_bcnt<<<NB, 256, 0, stream>>>(rec, gcur, cnt_i);
    k_chunk_sum<<<SCAN_NBLK, 64, 0, stream>>>(cnt_i, partial);
    k_scan_partials<<<1, 64, 0, stream>>>(partial, row_start);
    k_chunk_scan<<<SCAN_NBLK, 64, 0, stream>>>(cnt_i, partial, row_start);
    k_place<<<NB, 256, 0, stream>>>(rec, gcur, row_start, csr);

    const int gmean_blocks = (N_NODES + 3) / 4;
    const int pair_blocks  = (N_PAIRS + 7) / 8;
    const int gemm_blocks  = 782;    // 782*4 waves, 2 node-tiles each (6250 total)

    // ---- layer 1: B1 = x@W1l ; B2 = x@W1r + b1 ; B2 = relu(mean(B1)+B2) ----
    mfma_dual_gemm<float><<<gemm_blocks, 256, 0, stream>>>(x, W1l, W1r, b1, B1, B2);
    gather_mean<true><<<gmean_blocks, 256, 0, stream>>>(B1, row_start, csr, B2);

    // ---- layer 2 (in-place): B1 = h1@W2l ; B2 = h1@W2r + b2 ; combine ----
    mfma_dual_gemm<ushort_t><<<gemm_blocks, 256, 0, stream>>>(B2, W2l, W2r, b2, B1, B2);
    gather_mean<false><<<gmean_blocks, 256, 0, stream>>>(B1, row_start, csr, B2);

    // ---- pair precompute: B1 = h2@Wp1[64:] (v) ; B2 = h2@Wp1[:64]+bp1 (u) ----
    mfma_dual_gemm<ushort_t><<<gemm_blocks, 256, 0, stream>>>(B2, Wp1 + CH * CH, Wp1, bp1, B1, B2);

    // ---- link predictor ----
    pair_pred<<<pair_blocks, 256, 0, stream>>>(B2, B1, p_a, p_b, Wp2, bp2, out);
}